// Round 1
// baseline (1602.112 us; speedup 1.0000x reference)
//
#include <hip/hip_runtime.h>
#include <math.h>

// Problem geometry (fixed by setup_inputs)
#define BB   4
#define CC   256
#define HH   96
#define WW   96
#define OO   256
#define K2q  9
#define HW   9216        // HH*WW
#define KDIM 2304        // CC*K2q
#define OFFC 18          // 2*K*K offset channels

// Deform GEMM tiling
#define MT 64            // output-channel tile
#define NT 64            // spatial-position tile
#define KC 64            // K chunk

// ---------------- Kernel 1: 3x3 offset conv (pad=1, stride=1) ----------------
// grid: BB * OFFC * 36 blocks; block = (b, oc, 256-position chunk)
__global__ __launch_bounds__(256)
void offset_conv_kernel(const float* __restrict__ x,
                        const float* __restrict__ w_off,
                        const float* __restrict__ b_off,
                        float* __restrict__ off)
{
    __shared__ float wsh[KDIM];
    int bid   = blockIdx.x;
    int chunk = bid % 36;
    int oc    = (bid / 36) % OFFC;
    int b     = bid / (36 * OFFC);

    for (int i = threadIdx.x; i < KDIM; i += 256)
        wsh[i] = w_off[oc * KDIM + i];
    __syncthreads();

    int pr = chunk * 256 + (int)threadIdx.x;
    int h = pr / WW, w = pr % WW;
    float acc = b_off[oc];
    const float* xb = x + (size_t)b * CC * HW;

    if (h >= 1 && h < HH - 1 && w >= 1 && w < WW - 1) {
        for (int c = 0; c < CC; ++c) {
            const float* xc = xb + c * HW + (h - 1) * WW + (w - 1);
            const float* wc = wsh + c * 9;
            #pragma unroll
            for (int di = 0; di < 3; ++di)
                #pragma unroll
                for (int dj = 0; dj < 3; ++dj)
                    acc = fmaf(xc[di * WW + dj], wc[di * 3 + dj], acc);
        }
    } else {
        for (int c = 0; c < CC; ++c) {
            const float* xc = xb + c * HW;
            const float* wc = wsh + c * 9;
            #pragma unroll
            for (int di = 0; di < 3; ++di) {
                int yy = h + di - 1;
                bool vy = (yy >= 0) & (yy < HH);
                #pragma unroll
                for (int dj = 0; dj < 3; ++dj) {
                    int xx = w + dj - 1;
                    bool vx = (xx >= 0) & (xx < WW);
                    float xv = (vy & vx) ? xc[yy * WW + xx] : 0.f;
                    acc = fmaf(xv, wc[di * 3 + dj], acc);
                }
            }
        }
    }
    off[(size_t)(b * OFFC + oc) * HW + pr] = acc;
}

// ---------------- Kernel 2: deformable conv as fused implicit GEMM ----------------
// out[b,o,p] = b_dc[o] + sum_{c,k} w_dc[o,c,k] * V[(c,k), p]
// grid: (OO/MT) * (BB*HW/NT) = 4 * 2304/4... = 2304 blocks; 256 threads.
__global__ __launch_bounds__(256)
void deform_conv_kernel(const float* __restrict__ x,
                        const float* __restrict__ off,
                        const float* __restrict__ w_dc,
                        const float* __restrict__ b_dc,
                        float* __restrict__ out)
{
    __shared__ float Wl[KC][MT + 4];     // stride 68 floats: rows 16B-aligned for float4 reads
    __shared__ float Vl[KC][NT];
    __shared__ int   midx[4][K2q][NT];   // corner-major: conflict-free lane-consecutive reads
    __shared__ float mwt[4][K2q][NT];

    int bid  = blockIdx.x;
    int ot   = bid & 3;          // o-tile (4 of them, fastest for L2 reuse of gathered x)
    int pt   = bid >> 2;         // position tile
    int pos0 = pt * NT;
    int b    = pos0 / HW;        // NT divides HW -> tiles never straddle batch
    int posr = pos0 % HW;

    int tid = threadIdx.x;

    // ---- Phase A: per-(tap, position) bilinear metadata (channel independent) ----
    const float* offb = off + (size_t)b * OFFC * HW;
    for (int s = tid; s < K2q * NT; s += 256) {
        int t = s / NT, j = s % NT;
        int pr = posr + j;
        int ho = pr / WW, wo = pr % WW;
        float dy = offb[(2 * t + 0) * HW + pr];
        float dx = offb[(2 * t + 1) * HW + pr];
        float py = (float)(ho - 1 + t / 3) + dy;
        float px = (float)(wo - 1 + t % 3) + dx;
        float y0f = floorf(py), x0f = floorf(px);
        int y0 = (int)y0f, x0 = (int)x0f;
        int y1 = y0 + 1,  x1 = x0 + 1;
        float ly = py - y0f, lx = px - x0f;
        float hy = 1.f - ly, hx = 1.f - lx;
        bool vy0 = (y0 >= 0) & (y0 < HH);
        bool vy1 = (y1 >= 0) & (y1 < HH);
        bool vx0 = (x0 >= 0) & (x0 < WW);
        bool vx1 = (x1 >= 0) & (x1 < WW);
        int cy0 = min(max(y0, 0), HH - 1), cy1 = min(max(y1, 0), HH - 1);
        int cx0 = min(max(x0, 0), WW - 1), cx1 = min(max(x1, 0), WW - 1);
        midx[0][t][j] = cy0 * WW + cx0;
        midx[1][t][j] = cy0 * WW + cx1;
        midx[2][t][j] = cy1 * WW + cx0;
        midx[3][t][j] = cy1 * WW + cx1;
        mwt[0][t][j] = (vy0 & vx0) ? hy * hx : 0.f;
        mwt[1][t][j] = (vy0 & vx1) ? hy * lx : 0.f;
        mwt[2][t][j] = (vy1 & vx0) ? ly * hx : 0.f;
        mwt[3][t][j] = (vy1 & vx1) ? ly * lx : 0.f;
    }
    __syncthreads();

    int j  = tid & 63;   // position within tile (lane-consecutive -> coalesced gathers)
    int kb = tid >> 6;   // wave id 0..3
    int to = tid >> 4;   // 0..15: o-group of 4
    int tp = tid & 15;   // 0..15: pos-group of 4
    const float* xb = x + (size_t)b * CC * HW;
    const float* wp = w_dc + (size_t)(ot * MT) * KDIM;

    float acc[4][4] = {};

    for (int k0 = 0; k0 < KDIM; k0 += KC) {
        // ---- stage W chunk: Wl[kk][o] (transposed), coalesced global reads ----
        #pragma unroll
        for (int r = 0; r < 16; ++r) {
            int o = kb + 4 * r;                       // wave-uniform o
            Wl[j][o] = wp[(size_t)o * KDIM + k0 + j]; // lanes: consecutive kk -> coalesced
        }
        // ---- gather V chunk: Vl[kk][j] via bilinear sampling ----
        #pragma unroll
        for (int r = 0; r < 16; ++r) {
            int kk = kb + 4 * r;
            int kg = k0 + kk;
            int c  = kg / 9;
            int t  = kg % 9;
            const float* xc = xb + c * HW;
            float v = mwt[0][t][j] * xc[midx[0][t][j]]
                    + mwt[1][t][j] * xc[midx[1][t][j]]
                    + mwt[2][t][j] * xc[midx[2][t][j]]
                    + mwt[3][t][j] * xc[midx[3][t][j]];
            Vl[kk][j] = v;
        }
        __syncthreads();

        // ---- 64x64 outer-product, 4x4 per thread ----
        #pragma unroll 16
        for (int kk = 0; kk < KC; ++kk) {
            float4 wv = *(const float4*)(&Wl[kk][to * 4]);
            float4 vv = *(const float4*)(&Vl[kk][tp * 4]);
            acc[0][0] = fmaf(wv.x, vv.x, acc[0][0]);
            acc[0][1] = fmaf(wv.x, vv.y, acc[0][1]);
            acc[0][2] = fmaf(wv.x, vv.z, acc[0][2]);
            acc[0][3] = fmaf(wv.x, vv.w, acc[0][3]);
            acc[1][0] = fmaf(wv.y, vv.x, acc[1][0]);
            acc[1][1] = fmaf(wv.y, vv.y, acc[1][1]);
            acc[1][2] = fmaf(wv.y, vv.z, acc[1][2]);
            acc[1][3] = fmaf(wv.y, vv.w, acc[1][3]);
            acc[2][0] = fmaf(wv.z, vv.x, acc[2][0]);
            acc[2][1] = fmaf(wv.z, vv.y, acc[2][1]);
            acc[2][2] = fmaf(wv.z, vv.z, acc[2][2]);
            acc[2][3] = fmaf(wv.z, vv.w, acc[2][3]);
            acc[3][0] = fmaf(wv.w, vv.x, acc[3][0]);
            acc[3][1] = fmaf(wv.w, vv.y, acc[3][1]);
            acc[3][2] = fmaf(wv.w, vv.z, acc[3][2]);
            acc[3][3] = fmaf(wv.w, vv.w, acc[3][3]);
        }
        __syncthreads();
    }

    // ---- epilogue: add bias, float4 stores ----
    int o0 = ot * MT + to * 4;
    float* outp = out + (size_t)b * OO * HW + posr + tp * 4;
    #pragma unroll
    for (int m = 0; m < 4; ++m) {
        float bm = b_dc[o0 + m];
        float4 res;
        res.x = acc[m][0] + bm;
        res.y = acc[m][1] + bm;
        res.z = acc[m][2] + bm;
        res.w = acc[m][3] + bm;
        *(float4*)(outp + (size_t)(o0 + m) * HW) = res;
    }
}

extern "C" void kernel_launch(void* const* d_in, const int* in_sizes, int n_in,
                              void* d_out, int out_size, void* d_ws, size_t ws_size,
                              hipStream_t stream)
{
    const float* x     = (const float*)d_in[0];
    const float* w_off = (const float*)d_in[1];
    const float* b_off = (const float*)d_in[2];
    const float* w_dc  = (const float*)d_in[3];
    const float* b_dc  = (const float*)d_in[4];
    float* out = (float*)d_out;
    float* off = (float*)d_ws;   // BB*OFFC*HW floats = 2.65 MB scratch

    offset_conv_kernel<<<BB * OFFC * 36, 256, 0, stream>>>(x, w_off, b_off, off);
    deform_conv_kernel<<<(OO / MT) * (BB * HW / NT), 256, 0, stream>>>(x, off, w_dc, b_dc, out);
}

// Round 2
// 998.316 us; speedup vs baseline: 1.6048x; 1.6048x over previous
//
#include <hip/hip_runtime.h>
#include <math.h>

#define BB   4
#define CC   256
#define HH   96
#define WW   96
#define OO   256
#define HW   9216        // HH*WW
#define KDIM 2304        // CC*9
#define OFFC 18

typedef short bf16x8 __attribute__((ext_vector_type(8)));
typedef float f32x4  __attribute__((ext_vector_type(4)));

__device__ __forceinline__ unsigned short f2bfu(float f) {
    unsigned u = __float_as_uint(f);
    unsigned r = (u + 0x7fffu + ((u >> 16) & 1u)) >> 16;   // RNE
    return (unsigned short)r;
}
__device__ __forceinline__ unsigned pack2(float lo, float hi) {
    return (unsigned)f2bfu(lo) | ((unsigned)f2bfu(hi) << 16);
}

// ---------------- Kernel 1: 3x3 offset conv, 6 oc per block ----------------
// grid: BB * 36 * 3 = 432 blocks, 256 threads. Thread: one position, 6 oc accs.
// Weights indexed wave-uniformly -> scalar loads; x window register-cached.
__global__ __launch_bounds__(256)
void offset_conv6_kernel(const float* __restrict__ x,
                         const float* __restrict__ w_off,
                         const float* __restrict__ b_off,
                         float* __restrict__ off)
{
    int bid   = blockIdx.x;
    int g     = bid % 3;
    int chunk = (bid / 3) % 36;
    int b     = bid / 108;
    int ocb   = g * 6;
    int pr    = chunk * 256 + (int)threadIdx.x;
    int oh    = pr / WW, ow = pr - oh * WW;
    const float* xb = x + (size_t)b * CC * HW;

    float acc[6];
    #pragma unroll
    for (int i = 0; i < 6; ++i) acc[i] = b_off[ocb + i];

    bool interior = (oh >= 1) & (oh < HH - 1) & (ow >= 1) & (ow < WW - 1);
    if (interior) {
        const float* xp = xb + (oh - 1) * WW + (ow - 1);
        float xv[9];
        #pragma unroll
        for (int t = 0; t < 9; ++t) xv[t] = xp[(t / 3) * WW + (t % 3)];
        for (int c = 0; c < CC; ++c) {
            float xn[9];
            if (c + 1 < CC) {
                const float* xq = xp + (size_t)(c + 1) * HW;
                #pragma unroll
                for (int t = 0; t < 9; ++t) xn[t] = xq[(t / 3) * WW + (t % 3)];
            }
            #pragma unroll
            for (int i = 0; i < 6; ++i) {
                const float* wr = w_off + ((size_t)(ocb + i) * CC + c) * 9;
                #pragma unroll
                for (int t = 0; t < 9; ++t)
                    acc[i] = fmaf(xv[t], wr[t], acc[i]);
            }
            #pragma unroll
            for (int t = 0; t < 9; ++t) xv[t] = xn[t];
        }
    } else {
        for (int c = 0; c < CC; ++c) {
            const float* xc = xb + (size_t)c * HW;
            float xv[9];
            #pragma unroll
            for (int t = 0; t < 9; ++t) {
                int yy = oh + t / 3 - 1, xx = ow + t % 3 - 1;
                xv[t] = (yy >= 0 && yy < HH && xx >= 0 && xx < WW) ? xc[yy * WW + xx] : 0.f;
            }
            #pragma unroll
            for (int i = 0; i < 6; ++i) {
                const float* wr = w_off + ((size_t)(ocb + i) * CC + c) * 9;
                #pragma unroll
                for (int t = 0; t < 9; ++t)
                    acc[i] = fmaf(xv[t], wr[t], acc[i]);
            }
        }
    }
    #pragma unroll
    for (int i = 0; i < 6; ++i)
        off[((size_t)b * OFFC + ocb + i) * HW + pr] = acc[i];
}

// ---------------- Kernel 2: deform conv, MFMA implicit GEMM ----------------
// D[p][o] = sum_k V[k][p] * W[o][k]   (out-transposed orientation)
// tile 128p x 128o, BK=64, 4 waves (2x2), 16x16x32 bf16 MFMA.
__global__ __launch_bounds__(256)
void deform_mfma_kernel(const float* __restrict__ x,
                        const float* __restrict__ off,
                        const float* __restrict__ w_dc,
                        const float* __restrict__ b_dc,
                        float* __restrict__ out)
{
    __shared__ __align__(16) char VlB[128 * 128];   // V: [p][k] bf16, 128B rows, XOR-swizzled
    __shared__ __align__(16) char WlB[128 * 128];   // W: [o][k] bf16
    __shared__ uint4 meta[9][128];                  // {base0, base1, w01pack, w23pack}

    const int tid  = threadIdx.x;
    const int ot   = blockIdx.x / 288;
    const int pt   = blockIdx.x % 288;
    const int pos0 = pt * 128;
    const int b    = pos0 / HW;
    const int posr = pos0 - b * HW;

    // ---- metadata: per (tap, position) bilinear sampling plan ----
    const float* offp = off + (size_t)b * OFFC * HW;
    for (int s = tid; s < 9 * 128; s += 256) {
        int tt = s >> 7, j = s & 127;
        int pr = posr + j;
        int oh = pr / WW, ow = pr - oh * WW;
        float dy = offp[(2 * tt) * HW + pr];
        float dx = offp[(2 * tt + 1) * HW + pr];
        float py = (float)(oh - 1 + tt / 3) + dy;
        float px = (float)(ow - 1 + (tt - (tt / 3) * 3)) + dx;
        float y0f = floorf(py), x0f = floorf(px);
        int y0 = (int)y0f, x0 = (int)x0f;
        float ly = py - y0f, lx = px - x0f;
        float wy0 = (y0 >= 0 && y0 < HH) ? 1.f - ly : 0.f;
        float wy1 = (y0 + 1 >= 0 && y0 + 1 < HH) ? ly : 0.f;
        float u0 = (x0 >= 0 && x0 < WW) ? 1.f - lx : 0.f;
        float u1 = (x0 + 1 >= 0 && x0 + 1 < WW) ? lx : 0.f;
        // shift true x-columns into the in-row pair [pb, pb+1]
        int pb = min(max(x0, 0), WW - 2);
        float s0, s1;
        if (x0 < 0)           { s0 = u1; s1 = 0.f; }   // pair=(0,1): col0 is corner x0+1
        else if (x0 > WW - 2) { s0 = 0.f; s1 = u0; }   // pair=(94,95): col95 is corner x0
        else                  { s0 = u0; s1 = u1; }
        int cy0 = min(max(y0, 0), HH - 1);
        int cy1 = min(max(y0 + 1, 0), HH - 1);
        uint4 m;
        m.x = (unsigned)(cy0 * WW + pb);
        m.y = (unsigned)(cy1 * WW + pb);
        m.z = pack2(wy0 * s0, wy0 * s1);
        m.w = pack2(wy1 * s0, wy1 * s1);
        meta[tt][j] = m;
    }
    __syncthreads();

    const int l15 = tid & 15;
    const int l4  = (tid >> 4) & 3;
    const int wav = tid >> 6;
    const int wp  = wav >> 1, wwo = wav & 1;
    const int j     = tid & 127;
    const int khalf = tid >> 7;
    const int wo_o  = tid >> 4;          // W staging: o sub-row 0..15
    const int wk    = (tid & 15) * 4;    // W staging: k group

    const float* wbase = w_dc + (size_t)(ot * 128) * KDIM;

    f32x4 acc[4][4];
    #pragma unroll
    for (int f = 0; f < 4; ++f)
        #pragma unroll
        for (int g = 0; g < 4; ++g)
            acc[f][g] = (f32x4){0.f, 0.f, 0.f, 0.f};

    for (int k0 = 0; k0 < KDIM; k0 += 64) {
        // ---- stage W chunk (fp32 global -> bf16 LDS, swizzled) ----
        #pragma unroll
        for (int r = 0; r < 8; ++r) {
            int o = r * 16 + wo_o;
            const float4 wv = *(const float4*)(wbase + (size_t)o * KDIM + k0 + wk);
            uint2 u;
            u.x = pack2(wv.x, wv.y);
            u.y = pack2(wv.z, wv.w);
            *(uint2*)(WlB + o * 128 + ((wk * 2) ^ ((o & 7) << 4))) = u;
        }
        // ---- gather V chunk: thread = (p=j, 32 consecutive k) ----
        {
            unsigned kb = (unsigned)(k0 + khalf * 32);
            unsigned c  = kb / 9u;
            unsigned tt = kb - c * 9u;
            const float* xc = x + (size_t)((unsigned)b * CC + c) * HW;
            char* vrow = VlB + j * 128;
            const unsigned swz = (unsigned)((j & 7) << 4);
            #pragma unroll
            for (int g = 0; g < 4; ++g) {
                float v[8];
                #pragma unroll
                for (int e = 0; e < 8; ++e) {
                    uint4 m = meta[tt][j];
                    float A0 = xc[m.x], A1 = xc[m.x + 1];
                    float B0 = xc[m.y], B1 = xc[m.y + 1];
                    float a0 = __uint_as_float(m.z << 16);
                    float a1 = __uint_as_float(m.z & 0xffff0000u);
                    float b0 = __uint_as_float(m.w << 16);
                    float b1 = __uint_as_float(m.w & 0xffff0000u);
                    v[e] = fmaf(a0, A0, fmaf(a1, A1, fmaf(b0, B0, b1 * B1)));
                    ++tt;
                    if (tt == 9u) { tt = 0u; xc += HW; }
                }
                uint4 pk;
                pk.x = pack2(v[0], v[1]); pk.y = pack2(v[2], v[3]);
                pk.z = pack2(v[4], v[5]); pk.w = pack2(v[6], v[7]);
                *(uint4*)(vrow + (((unsigned)(khalf * 64 + g * 16)) ^ swz)) = pk;
            }
        }
        __syncthreads();

        // ---- 2 k-steps x 16 MFMA ----
        #pragma unroll
        for (int ks = 0; ks < 2; ++ks) {
            bf16x8 a[4], bw[4];
            #pragma unroll
            for (int f = 0; f < 4; ++f) {
                int p_loc = wp * 64 + f * 16 + l15;
                a[f] = *(const bf16x8*)(VlB + p_loc * 128 +
                                        ((ks * 64 + l4 * 16) ^ ((p_loc & 7) << 4)));
            }
            #pragma unroll
            for (int g = 0; g < 4; ++g) {
                int o_loc = wwo * 64 + g * 16 + l15;
                bw[g] = *(const bf16x8*)(WlB + o_loc * 128 +
                                         ((ks * 64 + l4 * 16) ^ ((o_loc & 7) << 4)));
            }
            #pragma unroll
            for (int f = 0; f < 4; ++f)
                #pragma unroll
                for (int g = 0; g < 4; ++g)
                    acc[f][g] = __builtin_amdgcn_mfma_f32_16x16x32_bf16(a[f], bw[g], acc[f][g], 0, 0, 0);
        }
        __syncthreads();
    }

    // ---- epilogue: bias + float4 stores (4 consecutive p per lane) ----
    #pragma unroll
    for (int g = 0; g < 4; ++g) {
        int og = ot * 128 + wwo * 64 + g * 16 + l15;
        float bias = b_dc[og];
        float* op = out + ((size_t)b * OO + og) * HW + posr + wp * 64 + l4 * 4;
        #pragma unroll
        for (int f = 0; f < 4; ++f) {
            f32x4 r = acc[f][g];
            float4 st;
            st.x = r[0] + bias; st.y = r[1] + bias;
            st.z = r[2] + bias; st.w = r[3] + bias;
            *(float4*)(op + f * 16) = st;
        }
    }
}

extern "C" void kernel_launch(void* const* d_in, const int* in_sizes, int n_in,
                              void* d_out, int out_size, void* d_ws, size_t ws_size,
                              hipStream_t stream)
{
    const float* x     = (const float*)d_in[0];
    const float* w_off = (const float*)d_in[1];
    const float* b_off = (const float*)d_in[2];
    const float* w_dc  = (const float*)d_in[3];
    const float* b_dc  = (const float*)d_in[4];
    float* out = (float*)d_out;
    float* off = (float*)d_ws;   // 4*18*9216 floats = 2.65 MB

    offset_conv6_kernel<<<BB * 36 * 3, 256, 0, stream>>>(x, w_off, b_off, off);
    deform_mfma_kernel<<<(OO / 128) * (BB * HW / 128), 256, 0, stream>>>(x, off, w_dc, b_dc, out);
}

// Round 3
// 396.061 us; speedup vs baseline: 4.0451x; 2.5206x over previous
//
#include <hip/hip_runtime.h>
#include <math.h>

#define BB   4
#define CC   256
#define HH   96
#define WW   96
#define OO   256
#define HW   9216        // HH*WW
#define KDIM 2304        // CC*9
#define OFFC 18
#define NKC  36          // K chunks of 64

typedef short bf16x8 __attribute__((ext_vector_type(8)));
typedef float f32x4  __attribute__((ext_vector_type(4)));

// ---- ws layout (split path) ----
#define WS_V_SZ    (36864ull * 4608ull)               // V bf16 [p][k], row 4608B, pre-swizzled
#define WS_WB_OFF  WS_V_SZ
#define WS_WB_SZ   (256ull * 4608ull)                 // W bf16 [o][k], pre-swizzled
#define WS_META_OFF (WS_WB_OFF + WS_WB_SZ)
#define WS_META_SZ (4ull * 9ull * 9216ull * 16ull)    // uint4 per (b,tap,p)
#define WS_NEED    (WS_META_OFF + WS_META_SZ)         // ~176.4 MB

__device__ __forceinline__ unsigned short f2bfu(float f) {
    unsigned u = __float_as_uint(f);
    unsigned r = (u + 0x7fffu + ((u >> 16) & 1u)) >> 16;   // RNE
    return (unsigned short)r;
}
__device__ __forceinline__ unsigned pack2(float lo, float hi) {
    return (unsigned)f2bfu(lo) | ((unsigned)f2bfu(hi) << 16);
}
__device__ __forceinline__ void gload16(const void* g, void* l) {
    __builtin_amdgcn_global_load_lds((const __attribute__((address_space(1))) void*)g,
                                     (__attribute__((address_space(3))) void*)l, 16, 0, 0);
}

__device__ __forceinline__ uint4 make_meta(int pr, int t, float dy, float dx) {
    int oh = pr / WW, ow = pr - oh * WW;
    float py = (float)(oh - 1 + t / 3) + dy;
    float px = (float)(ow - 1 + (t % 3)) + dx;
    float y0f = floorf(py), x0f = floorf(px);
    int y0 = (int)y0f, x0 = (int)x0f;
    float ly = py - y0f, lx = px - x0f;
    float wy0 = (y0 >= 0 && y0 < HH) ? 1.f - ly : 0.f;
    float wy1 = (y0 + 1 >= 0 && y0 + 1 < HH) ? ly : 0.f;
    float u0 = (x0 >= 0 && x0 < WW) ? 1.f - lx : 0.f;
    float u1 = (x0 + 1 >= 0 && x0 + 1 < WW) ? lx : 0.f;
    int pb = min(max(x0, 0), WW - 2);
    float s0, s1;
    if (x0 < 0)           { s0 = u1; s1 = 0.f; }
    else if (x0 > WW - 2) { s0 = 0.f; s1 = u0; }
    else                  { s0 = u0; s1 = u1; }
    int cy0 = min(max(y0, 0), HH - 1);
    int cy1 = min(max(y0 + 1, 0), HH - 1);
    uint4 m;
    m.x = (unsigned)(cy0 * WW + pb);
    m.y = (unsigned)(cy1 * WW + pb);
    m.z = pack2(wy0 * s0, wy0 * s1);
    m.w = pack2(wy1 * s0, wy1 * s1);
    return m;
}

// ================= SPLIT PATH =================

// ---- Kernel A: offset conv via MFMA (64p x 32oc tile) + direct meta emission ----
__global__ __launch_bounds__(256)
void offset_meta_kernel(const float* __restrict__ x,
                        const float* __restrict__ w_off,
                        const float* __restrict__ b_off,
                        uint4* __restrict__ meta_ws)
{
    __shared__ __align__(16) char Asw[64 * 128];
    __shared__ __align__(16) char Wl[32 * 128];
    __shared__ float Dsh[64][21];

    const int tid = threadIdx.x;
    const int b   = blockIdx.x / 144;
    const int pr0 = (blockIdx.x % 144) * 64;
    const float* xb = x + (size_t)b * CC * HW;

    const int l15 = tid & 15;
    const int l4  = (tid >> 4) & 3;
    const int wav = tid >> 6;
    const int sp  = tid & 63;       // A staging: p row
    const int kq  = tid >> 6;       // A staging: k quarter
    const int so  = tid >> 3;       // W staging: o row 0..31
    const int skg = (tid & 7) * 8;  // W staging: k start within chunk

    const int prg = pr0 + sp;
    const int oh = prg / WW, ow = prg - (prg / WW) * WW;

    f32x4 acc[2];
    acc[0] = (f32x4){0.f, 0.f, 0.f, 0.f};
    acc[1] = (f32x4){0.f, 0.f, 0.f, 0.f};

    for (int kc = 0; kc < NKC; ++kc) {
        // stage W (fp32 -> bf16, swizzled); rows 18..31 zero
        {
            int k0 = kc * 64 + skg;
            uint4 pk;
            if (so < OFFC) {
                const float* wr = w_off + (size_t)so * KDIM + k0;
                pk.x = pack2(wr[0], wr[1]); pk.y = pack2(wr[2], wr[3]);
                pk.z = pack2(wr[4], wr[5]); pk.w = pack2(wr[6], wr[7]);
            } else { pk.x = pk.y = pk.z = pk.w = 0u; }
            *(uint4*)(Wl + so * 128 + ((skg * 2) ^ ((so & 7) << 4))) = pk;
        }
        // stage A: static-tap gather, 16 elems/thread
        {
            int kg = kc * 64 + kq * 16;
            unsigned c = (unsigned)kg / 9u, tt = (unsigned)kg - c * 9u;
            float v[16];
            #pragma unroll
            for (int e = 0; e < 16; ++e) {
                int iy = oh + (int)(tt / 3u) - 1;
                int ix = ow + (int)(tt % 3u) - 1;
                bool ok = (iy >= 0) & (iy < HH) & (ix >= 0) & (ix < WW);
                v[e] = ok ? xb[(size_t)c * HW + iy * WW + ix] : 0.f;
                ++tt; if (tt == 9u) { tt = 0u; ++c; }
            }
            char* arow = Asw + sp * 128;
            unsigned swz = (unsigned)((sp & 7) << 4);
            uint4 p0, p1;
            p0.x = pack2(v[0], v[1]);   p0.y = pack2(v[2], v[3]);
            p0.z = pack2(v[4], v[5]);   p0.w = pack2(v[6], v[7]);
            p1.x = pack2(v[8], v[9]);   p1.y = pack2(v[10], v[11]);
            p1.z = pack2(v[12], v[13]); p1.w = pack2(v[14], v[15]);
            *(uint4*)(arow + (((unsigned)(kq * 32 + 0)) ^ swz)) = p0;
            *(uint4*)(arow + (((unsigned)(kq * 32 + 16)) ^ swz)) = p1;
        }
        __syncthreads();
        // MFMA: wave handles p-frag wav*16, oc-frags 0..1
        {
            int p_loc = wav * 16 + l15;
            unsigned aswz = (unsigned)((p_loc & 7) << 4);
            #pragma unroll
            for (int ks = 0; ks < 2; ++ks) {
                bf16x8 a = *(const bf16x8*)(Asw + p_loc * 128 + ((ks * 64 + l4 * 16) ^ aswz));
                #pragma unroll
                for (int g = 0; g < 2; ++g) {
                    int o_loc = g * 16 + l15;
                    bf16x8 bw = *(const bf16x8*)(Wl + o_loc * 128 +
                                                 ((ks * 64 + l4 * 16) ^ ((o_loc & 7) << 4)));
                    acc[g] = __builtin_amdgcn_mfma_f32_16x16x32_bf16(a, bw, acc[g], 0, 0, 0);
                }
            }
        }
        __syncthreads();
    }

    // D -> LDS (rows p, cols oc<18), add bias
    #pragma unroll
    for (int g = 0; g < 2; ++g) {
        int o = g * 16 + l15;
        if (o < OFFC) {
            float bo = b_off[o];
            #pragma unroll
            for (int r = 0; r < 4; ++r)
                Dsh[wav * 16 + l4 * 4 + r][o] = acc[g][r] + bo;
        }
    }
    __syncthreads();
    // meta: 9 taps x 64 positions
    for (int s = tid; s < 9 * 64; s += 256) {
        int t = s >> 6, pl = s & 63;
        int pr = pr0 + pl;
        float dy = Dsh[pl][2 * t];
        float dx = Dsh[pl][2 * t + 1];
        meta_ws[((size_t)b * 9 + t) * HW + pr] = make_meta(pr, t, dy, dx);
    }
}

// ---- Kernel B: w_dc fp32 -> bf16 pre-swizzled ----
__global__ __launch_bounds__(256)
void wconv_kernel(const float* __restrict__ w_dc, char* __restrict__ wb)
{
    int idx = blockIdx.x * 256 + (int)threadIdx.x;   // 73728
    int o  = idx / 288;
    int kg = idx - o * 288;
    int k0 = kg * 8;
    const float* wr = w_dc + (size_t)o * KDIM + k0;
    uint4 pk;
    pk.x = pack2(wr[0], wr[1]); pk.y = pack2(wr[2], wr[3]);
    pk.z = pack2(wr[4], wr[5]); pk.w = pack2(wr[6], wr[7]);
    int kin2 = (k0 & 63) * 2;
    *(uint4*)(wb + (size_t)o * 4608 + (k0 >> 6) * 128 + (kin2 ^ ((o & 7) << 4))) = pk;
}

// ---- Kernel C: bilinear gather -> V[p][k] bf16 (pre-swizzled rows) ----
__global__ __launch_bounds__(256)
void gather_kernel(const float* __restrict__ x,
                   const uint4* __restrict__ meta_ws,
                   char* __restrict__ Vg)
{
    __shared__ uint4 meta[9][128];
    __shared__ __align__(16) char Vl[128 * 128];

    int bid = blockIdx.x;
    int pt = bid / NKC, kc = bid - pt * NKC;
    int b = pt / 72;
    int posr = (pt - b * 72) * 128;
    int tid = threadIdx.x;

    for (int s = tid; s < 9 * 128; s += 256) {
        int t = s >> 7, j = s & 127;
        meta[t][j] = meta_ws[((size_t)b * 9 + t) * HW + posr + j];
    }
    __syncthreads();

    int j = tid & 127, khalf = tid >> 7;
    {
        unsigned kb = (unsigned)(kc * 64 + khalf * 32);
        unsigned c  = kb / 9u;
        unsigned tt = kb - c * 9u;
        const float* xc = x + (size_t)((unsigned)b * CC + c) * HW;
        char* vrow = Vl + j * 128;
        const unsigned swz = (unsigned)((j & 7) << 4);
        #pragma unroll
        for (int g = 0; g < 4; ++g) {
            float v[8];
            #pragma unroll
            for (int e = 0; e < 8; ++e) {
                uint4 m = meta[tt][j];
                float A0 = xc[m.x], A1 = xc[m.x + 1];
                float B0 = xc[m.y], B1 = xc[m.y + 1];
                float a0 = __uint_as_float(m.z << 16);
                float a1 = __uint_as_float(m.z & 0xffff0000u);
                float b0 = __uint_as_float(m.w << 16);
                float b1 = __uint_as_float(m.w & 0xffff0000u);
                v[e] = fmaf(a0, A0, fmaf(a1, A1, fmaf(b0, B0, b1 * B1)));
                ++tt;
                if (tt == 9u) { tt = 0u; xc += HW; }
            }
            uint4 pk;
            pk.x = pack2(v[0], v[1]); pk.y = pack2(v[2], v[3]);
            pk.z = pack2(v[4], v[5]); pk.w = pack2(v[6], v[7]);
            *(uint4*)(vrow + (((unsigned)(khalf * 64 + g * 16)) ^ swz)) = pk;
        }
    }
    __syncthreads();

    // coalesced write-out: LDS (already swizzled content) -> V rows, 128B/row chunk
    char* dst = Vg + (size_t)(pt * 128) * 4608 + (size_t)kc * 128;
    #pragma unroll
    for (int i = 0; i < 4; ++i) {
        int idx = i * 256 + tid;
        int row = idx >> 3, colg = (idx & 7) * 16;
        *(uint4*)(dst + (size_t)row * 4608 + colg) =
            *(const uint4*)(Vl + row * 128 + colg);
    }
}

// ---- Kernel D: streaming GEMM, 2-phase double-buffered, global_load_lds ----
__global__ __launch_bounds__(256)
void gemm_kernel(const char* __restrict__ Vg, const char* __restrict__ Wb,
                 const float* __restrict__ b_dc, float* __restrict__ out)
{
    __shared__ __align__(16) char Ab[2][128 * 128];
    __shared__ __align__(16) char Bb[2][128 * 128];

    int bid = blockIdx.x;
    int swzb = (bid & 7) * 72 + (bid >> 3);   // bijective XCD swizzle (576 % 8 == 0)
    int pt = swzb >> 1, ot = swzb & 1;
    int tid = threadIdx.x;
    int lane = tid & 63, wav = tid >> 6;
    const int l15 = tid & 15, l4 = (tid >> 4) & 3;
    const int wp = wav >> 1, wo = wav & 1;

    const char* Ag = Vg + (size_t)(pt * 128) * 4608;
    const char* Bg = Wb + (size_t)(ot * 128) * 4608;
    const int rsub = lane >> 3;
    const int csub = (lane & 7) * 16;

    f32x4 acc[4][4];
    #pragma unroll
    for (int f = 0; f < 4; ++f)
        #pragma unroll
        for (int g = 0; g < 4; ++g)
            acc[f][g] = (f32x4){0.f, 0.f, 0.f, 0.f};

#define STAGE(bufi, t) {                                                        \
        const char* ag = Ag + (size_t)(t) * 128;                                \
        const char* bg = Bg + (size_t)(t) * 128;                                \
        _Pragma("unroll")                                                       \
        for (int i = 0; i < 4; ++i) {                                           \
            int r0 = wav * 32 + i * 8;                                          \
            gload16(ag + (size_t)(r0 + rsub) * 4608 + csub, &Ab[bufi][r0 * 128]);\
            gload16(bg + (size_t)(r0 + rsub) * 4608 + csub, &Bb[bufi][r0 * 128]);\
        } }

    STAGE(0, 0);
    __syncthreads();

    int cur = 0;
    for (int t = 0; t < NKC; ++t) {
        if (t + 1 < NKC) STAGE(cur ^ 1, t + 1);
        #pragma unroll
        for (int ks = 0; ks < 2; ++ks) {
            bf16x8 a[4], bw[4];
            #pragma unroll
            for (int f = 0; f < 4; ++f) {
                int p_loc = wp * 64 + f * 16 + l15;
                a[f] = *(const bf16x8*)(Ab[cur] + p_loc * 128 +
                                        ((ks * 64 + l4 * 16) ^ ((p_loc & 7) << 4)));
            }
            #pragma unroll
            for (int g = 0; g < 4; ++g) {
                int o_loc = wo * 64 + g * 16 + l15;
                bw[g] = *(const bf16x8*)(Bb[cur] + o_loc * 128 +
                                         ((ks * 64 + l4 * 16) ^ ((o_loc & 7) << 4)));
            }
            #pragma unroll
            for (int f = 0; f < 4; ++f)
                #pragma unroll
                for (int g = 0; g < 4; ++g)
                    acc[f][g] = __builtin_amdgcn_mfma_f32_16x16x32_bf16(a[f], bw[g], acc[f][g], 0, 0, 0);
        }
        __syncthreads();
        cur ^= 1;
    }

    int b = pt / 72;
    int posr = (pt - b * 72) * 128;
    #pragma unroll
    for (int g = 0; g < 4; ++g) {
        int og = ot * 128 + wo * 64 + g * 16 + l15;
        float bias = b_dc[og];
        float* op = out + ((size_t)b * OO + og) * HW + posr + wp * 64 + l4 * 4;
        #pragma unroll
        for (int f = 0; f < 4; ++f) {
            f32x4 r = acc[f][g];
            float4 st;
            st.x = r[0] + bias; st.y = r[1] + bias;
            st.z = r[2] + bias; st.w = r[3] + bias;
            *(float4*)(op + f * 16) = st;
        }
    }
}

// ================= FALLBACK PATH (round-2, verified) =================

__global__ __launch_bounds__(256)
void offset_conv6_kernel(const float* __restrict__ x,
                         const float* __restrict__ w_off,
                         const float* __restrict__ b_off,
                         float* __restrict__ off)
{
    int bid   = blockIdx.x;
    int g     = bid % 3;
    int chunk = (bid / 3) % 36;
    int b     = bid / 108;
    int ocb   = g * 6;
    int pr    = chunk * 256 + (int)threadIdx.x;
    int oh    = pr / WW, ow = pr % WW;
    const float* xb = x + (size_t)b * CC * HW;

    float acc[6];
    #pragma unroll
    for (int i = 0; i < 6; ++i) acc[i] = b_off[ocb + i];

    bool interior = (oh >= 1) & (oh < HH - 1) & (ow >= 1) & (ow < WW - 1);
    if (interior) {
        const float* xp = xb + (oh - 1) * WW + (ow - 1);
        float xv[9];
        #pragma unroll
        for (int t = 0; t < 9; ++t) xv[t] = xp[(t / 3) * WW + (t % 3)];
        for (int c = 0; c < CC; ++c) {
            float xn[9];
            if (c + 1 < CC) {
                const float* xq = xp + (size_t)(c + 1) * HW;
                #pragma unroll
                for (int t = 0; t < 9; ++t) xn[t] = xq[(t / 3) * WW + (t % 3)];
            }
            #pragma unroll
            for (int i = 0; i < 6; ++i) {
                const float* wr = w_off + ((size_t)(ocb + i) * CC + c) * 9;
                #pragma unroll
                for (int t = 0; t < 9; ++t)
                    acc[i] = fmaf(xv[t], wr[t], acc[i]);
            }
            #pragma unroll
            for (int t = 0; t < 9; ++t) xv[t] = xn[t];
        }
    } else {
        for (int c = 0; c < CC; ++c) {
            const float* xc = xb + (size_t)c * HW;
            float xv[9];
            #pragma unroll
            for (int t = 0; t < 9; ++t) {
                int yy = oh + t / 3 - 1, xx = ow + t % 3 - 1;
                xv[t] = (yy >= 0 && yy < HH && xx >= 0 && xx < WW) ? xc[yy * WW + xx] : 0.f;
            }
            #pragma unroll
            for (int i = 0; i < 6; ++i) {
                const float* wr = w_off + ((size_t)(ocb + i) * CC + c) * 9;
                #pragma unroll
                for (int t = 0; t < 9; ++t)
                    acc[i] = fmaf(xv[t], wr[t], acc[i]);
            }
        }
    }
    #pragma unroll
    for (int i = 0; i < 6; ++i)
        off[((size_t)b * OFFC + ocb + i) * HW + pr] = acc[i];
}

__global__ __launch_bounds__(256)
void deform_mfma_kernel(const float* __restrict__ x,
                        const float* __restrict__ off,
                        const float* __restrict__ w_dc,
                        const float* __restrict__ b_dc,
                        float* __restrict__ out)
{
    __shared__ __align__(16) char VlB[128 * 128];
    __shared__ __align__(16) char WlB[128 * 128];
    __shared__ uint4 meta[9][128];

    const int tid  = threadIdx.x;
    const int ot   = blockIdx.x / 288;
    const int pt   = blockIdx.x % 288;
    const int pos0 = pt * 128;
    const int b    = pos0 / HW;
    const int posr = pos0 - b * HW;

    const float* offp = off + (size_t)b * OFFC * HW;
    for (int s = tid; s < 9 * 128; s += 256) {
        int tt = s >> 7, j = s & 127;
        int pr = posr + j;
        float dy = offp[(2 * tt) * HW + pr];
        float dx = offp[(2 * tt + 1) * HW + pr];
        meta[tt][j] = make_meta(pr, tt, dy, dx);
    }
    __syncthreads();

    const int l15 = tid & 15;
    const int l4  = (tid >> 4) & 3;
    const int wav = tid >> 6;
    const int wp  = wav >> 1, wwo = wav & 1;
    const int j     = tid & 127;
    const int khalf = tid >> 7;
    const int wo_o  = tid >> 4;
    const int wk    = (tid & 15) * 4;

    const float* wbase = w_dc + (size_t)(ot * 128) * KDIM;

    f32x4 acc[4][4];
    #pragma unroll
    for (int f = 0; f < 4; ++f)
        #pragma unroll
        for (int g = 0; g < 4; ++g)
            acc[f][g] = (f32x4){0.f, 0.f, 0.f, 0.f};

    for (int k0 = 0; k0 < KDIM; k0 += 64) {
        #pragma unroll
        for (int r = 0; r < 8; ++r) {
            int o = r * 16 + wo_o;
            const float4 wv = *(const float4*)(wbase + (size_t)o * KDIM + k0 + wk);
            uint2 u;
            u.x = pack2(wv.x, wv.y);
            u.y = pack2(wv.z, wv.w);
            *(uint2*)(WlB + o * 128 + ((wk * 2) ^ ((o & 7) << 4))) = u;
        }
        {
            unsigned kb = (unsigned)(k0 + khalf * 32);
            unsigned c  = kb / 9u;
            unsigned tt = kb - c * 9u;
            const float* xc = x + (size_t)((unsigned)b * CC + c) * HW;
            char* vrow = VlB + j * 128;
            const unsigned swz = (unsigned)((j & 7) << 4);
            #pragma unroll
            for (int g = 0; g < 4; ++g) {
                float v[8];
                #pragma unroll
                for (int e = 0; e < 8; ++e) {
                    uint4 m = meta[tt][j];
                    float A0 = xc[m.x], A1 = xc[m.x + 1];
                    float B0 = xc[m.y], B1 = xc[m.y + 1];
                    float a0 = __uint_as_float(m.z << 16);
                    float a1 = __uint_as_float(m.z & 0xffff0000u);
                    float b0 = __uint_as_float(m.w << 16);
                    float b1 = __uint_as_float(m.w & 0xffff0000u);
                    v[e] = fmaf(a0, A0, fmaf(a1, A1, fmaf(b0, B0, b1 * B1)));
                    ++tt;
                    if (tt == 9u) { tt = 0u; xc += HW; }
                }
                uint4 pk;
                pk.x = pack2(v[0], v[1]); pk.y = pack2(v[2], v[3]);
                pk.z = pack2(v[4], v[5]); pk.w = pack2(v[6], v[7]);
                *(uint4*)(vrow + (((unsigned)(khalf * 64 + g * 16)) ^ swz)) = pk;
            }
        }
        __syncthreads();

        #pragma unroll
        for (int ks = 0; ks < 2; ++ks) {
            bf16x8 a[4], bw[4];
            #pragma unroll
            for (int f = 0; f < 4; ++f) {
                int p_loc = wp * 64 + f * 16 + l15;
                a[f] = *(const bf16x8*)(VlB + p_loc * 128 +
                                        ((ks * 64 + l4 * 16) ^ ((p_loc & 7) << 4)));
            }
            #pragma unroll
            for (int g = 0; g < 4; ++g) {
                int o_loc = wwo * 64 + g * 16 + l15;
                bw[g] = *(const bf16x8*)(WlB + o_loc * 128 +
                                         ((ks * 64 + l4 * 16) ^ ((o_loc & 7) << 4)));
            }
            #pragma unroll
            for (int f = 0; f < 4; ++f)
                #pragma unroll
                for (int g = 0; g < 4; ++g)
                    acc[f][g] = __builtin_amdgcn_mfma_f32_16x16x32_bf16(a[f], bw[g], acc[f][g], 0, 0, 0);
        }
        __syncthreads();
    }

    #pragma unroll
    for (int g = 0; g < 4; ++g) {
        int og = ot * 128 + wwo * 64 + g * 16 + l15;
        float bias = b_dc[og];
        float* op = out + ((size_t)b * OO + og) * HW + posr + wp * 64 + l4 * 4;
        #pragma unroll
        for (int f = 0; f < 4; ++f) {
            f32x4 r = acc[f][g];
            float4 st;
            st.x = r[0] + bias; st.y = r[1] + bias;
            st.z = r[2] + bias; st.w = r[3] + bias;
            *(float4*)(op + f * 16) = st;
        }
    }
}

extern "C" void kernel_launch(void* const* d_in, const int* in_sizes, int n_in,
                              void* d_out, int out_size, void* d_ws, size_t ws_size,
                              hipStream_t stream)
{
    const float* x     = (const float*)d_in[0];
    const float* w_off = (const float*)d_in[1];
    const float* b_off = (const float*)d_in[2];
    const float* w_dc  = (const float*)d_in[3];
    const float* b_dc  = (const float*)d_in[4];
    float* out = (float*)d_out;

    if (ws_size >= WS_NEED) {
        char*  ws   = (char*)d_ws;
        char*  Vg   = ws;
        char*  Wb   = ws + WS_WB_OFF;
        uint4* meta = (uint4*)(ws + WS_META_OFF);
        offset_meta_kernel<<<BB * 144, 256, 0, stream>>>(x, w_off, b_off, meta);
        wconv_kernel<<<288, 256, 0, stream>>>(w_dc, Wb);
        gather_kernel<<<288 * NKC, 256, 0, stream>>>(x, meta, Vg);
        gemm_kernel<<<576, 256, 0, stream>>>(Vg, Wb, b_dc, out);
    } else {
        float* off = (float*)d_ws;
        offset_conv6_kernel<<<BB * 36 * 3, 256, 0, stream>>>(x, w_off, b_off, off);
        deform_mfma_kernel<<<(OO / 128) * (BB * HW / 128), 256, 0, stream>>>(x, off, w_dc, b_dc, out);
    }
}